// Round 8
// baseline (202.397 us; speedup 1.0000x reference)
//
#include <hip/hip_runtime.h>
#include <hip/hip_bf16.h>
#include <math.h>
#include <stdint.h>

#define B_ 64
#define L_ 2048
#define H_ 128
#define O_ 128
#define N_ 256
#define CH_ 128      // timesteps per full chunk (lamCCr granularity)
#define NCH_ 16      // full chunks
#define HB_ 64       // timesteps per half-chunk block
#define SPH_ 4       // strips (16 t) per half-chunk

using f32x4 = __attribute__((ext_vector_type(4))) float;
using i32x4 = __attribute__((ext_vector_type(4))) int;
using i32x2 = __attribute__((ext_vector_type(2))) int;
using h16x8 = __attribute__((ext_vector_type(8))) _Float16;

__device__ __forceinline__ unsigned short f16_bits(float v) {
    _Float16 h = (_Float16)v;                 // RNE convert
    return __builtin_bit_cast(unsigned short, h);
}
__device__ __forceinline__ int pack_f16(float a, float b) {
    return (int)((unsigned)f16_bits(a) | ((unsigned)f16_bits(b) << 16));
}
__device__ __forceinline__ float2 cmul(float2 a, float2 b) {
    return make_float2(a.x * b.x - a.y * b.y, a.x * b.y + a.y * b.x);
}

// ---------------------------------------------------------------------------
// prep: every block self-computes the nu-sorted permutation (rank 0 = slowest
// decay), then fills its slice of: B2Tr (fp16 (gamma*B)^T, rank-ordered cols),
// lamjR[rank][j]=lam^(15-j), lam16R=lam^16, lamCCr[c][rank]=lam^(128*(15-c)),
// nuR, perm, and zeroes X.
// ---------------------------------------------------------------------------
__global__ void prep_kernel(const float* __restrict__ nu_log, const float* __restrict__ theta_log,
                            const float* __restrict__ gamma_log, const float* __restrict__ B_re,
                            const float* __restrict__ B_im, unsigned short* __restrict__ B2Tr,
                            float2* __restrict__ lamjR, float2* __restrict__ lam16R,
                            float2* __restrict__ lamCCr, float* __restrict__ nuR,
                            int* __restrict__ perm, float* __restrict__ X) {
    __shared__ float nu_s[N_];
    __shared__ int perm_s[N_];
    const int t = threadIdx.x;
    float nu = expf(nu_log[t]);
    nu_s[t] = nu;
    __syncthreads();
    {
        int rank = 0;
        for (int j = 0; j < N_; ++j) {
            float vj = nu_s[j];
            rank += (vj < nu || (vj == nu && j < t)) ? 1 : 0;
        }
        perm_s[rank] = t;
    }
    __syncthreads();
    const int bb = blockIdx.x;
    if (bb < 64) {
        #pragma unroll
        for (int kk = 0; kk < 4; ++kk) {
            int e = bb * 1024 + kk * 256 + t;       // 0..65535
            int part = e >> 15, rank = (e >> 7) & 255, h = e & 127;
            int n = perm_s[rank];
            float g = expf(gamma_log[n]);
            float v = (part ? B_im : B_re)[n * H_ + h] * g;
            B2Tr[e] = f16_bits(v);
        }
    } else if (bb == 64) {
        int r = t, n = perm_s[r];
        float nun = nu_s[n];
        double th = (double)expf(theta_log[n]);
        double rr = exp(-(double)nun);
        double sn, cs;
        sincos(th, &sn, &cs);
        double lre = rr * cs, lim = rr * sn;
        double pre = 1.0, pim = 0.0;
        for (int k = 0; k < 16; ++k) {
            lamjR[r * 16 + 15 - k] = make_float2((float)pre, (float)pim);
            double t1 = pre * lre - pim * lim, t2 = pre * lim + pim * lre;
            pre = t1; pim = t2;
        }
        lam16R[r] = make_float2((float)pre, (float)pim);   // lam^16
        nuR[r] = nun;
        perm[r] = n;
        double wre = pre, wim = pim;                        // -> lam^128
        for (int i = 0; i < 3; ++i) {
            double a = wre * wre - wim * wim, b2 = 2.0 * wre * wim;
            wre = a; wim = b2;
        }
        double are = 1.0, aim = 0.0;
        for (int c = 15; c >= 0; --c) {
            lamCCr[c * N_ + r] = make_float2((float)are, (float)aim);
            double a = are * wre - aim * wim, b2 = are * wim + aim * wre;
            are = a; aim = b2;
        }
    } else {
        int idx = (bb - 65) * 1024 + t * 4;                 // 32 blocks x 1024 floats
        f32x4 z = {0.f, 0.f, 0.f, 0.f};
        *(f32x4*)&X[idx] = z;
    }
}

// ---------------------------------------------------------------------------
// scan (round 8): HALF-CHUNK blocks — 2048 blocks x 256 threads (4 waves),
// 8 blocks/CU (wave-slot limited). Rationale: the 8-wave/block version left
// scan ~20 us above its 11 us BW floor across 5 falsified theories; the
// surviving one is barrier-convoy granularity — all waves of a block drain at
// ONE barrier gated by the slowest of the block's line-fetches, and with only
// 4 convoys/CU (r4) the synchronized drains leave the CU idle (r6's 1/CU was
// worst; m13-style streaming with many small independent units hits 6.3TB/s).
// 8 smaller convoys/CU double the independent streams at equal in-flight
// loads. Per-wave phase-2 work unchanged (4 pairs x <=4 strips vs 2 x 8).
//  - block bx: half-chunk ch = bx>>6 (c = ch>>1, h = ch&1), b = bx&63;
//    XCD spread via bx%8 = b%8.
//  - wave g owns pairs {g, 7-g, 8+g, 15-g} (nu-rank balanced).
//  - strip alive iff nu*(base_e - 16s) <= 35, base_e = 2032-128c-64h.
//  - epilogue rotation: lamCCr[c] * (lam^64 if h==0) aligns half-end to
//    sequence end (P = 1984-128c-64h = (1920-128c) + 64*(1-h)).
// Phase 1: per wave-instr contiguous 1 KB (lane i <- base+i*16B); pack fp16,
// XOR-swizzled LDS image (unit = (c4>>1) ^ (r&15)), rows 0..63, one barrier.
// Phase 2 numerics per strip identical to r4 (same pack/gates/rescale).
// ---------------------------------------------------------------------------
__global__ __launch_bounds__(256, 8)
void scan_kernel(const float* __restrict__ u, const unsigned short* __restrict__ B2Tr,
                 const float2* __restrict__ lamjR, const float2* __restrict__ lam16R,
                 const float2* __restrict__ lamCCr, const float* __restrict__ nuR,
                 const int* __restrict__ perm, float* __restrict__ X) {
    const int bx = blockIdx.x;          // 0..2047
    const int ch = bx >> 6;             // half-chunk 0..31
    const int b  = bx & 63;
    const int c  = ch >> 1;             // full chunk 0..15
    const int h  = ch & 1;              // half 0..1
    const int tid = threadIdx.x;        // 0..255

    __shared__ __align__(16) unsigned short Asm[HB_ * H_];   // 16 KB fp16 image

    // ---- phase 1: issue half-chunk loads (contiguous 1 KB per wave instr) ----
    const float* gsrc = u + ((size_t)b * L_ + (size_t)(c * CH_ + h * HB_)) * H_;
    f32x4 Lv[8];
    #pragma unroll
    for (int k = 0; k < 8; ++k)
        Lv[k] = *(const f32x4*)(gsrc + k * 1024 + tid * 4);

    // ---- hoisted phase-2 setup (hides under load latency) ----
    const int g = tid >> 6;             // wave 0..3
    const int lane = tid & 63;
    const int m = lane & 15, q = lane >> 4;
    const int pid0 = g, pid1 = 7 - g, pid2 = 8 + g, pid3 = 15 - g;
    const float base_e = 2032.0f - 128.0f * (float)c - 64.0f * (float)h;
    const float nv0 = nuR[pid0 * 16];
    const float nv1 = nuR[pid1 * 16];
    const float nv2 = nuR[pid2 * 16];
    const float nv3 = nuR[pid3 * 16];
    int sp0 = (int)ceilf((base_e - 35.0f / nv0) * 0.0625f); if (sp0 < 0) sp0 = 0;
    int sp1 = (int)ceilf((base_e - 35.0f / nv1) * 0.0625f); if (sp1 < 0) sp1 = 0;
    int sp2 = (int)ceilf((base_e - 35.0f / nv2) * 0.0625f); if (sp2 < 0) sp2 = 0;
    int sp3 = (int)ceilf((base_e - 35.0f / nv3) * 0.0625f); if (sp3 < 0) sp3 = 0;

    // ---- phase 1 cont.: pack + swizzled LDS store ----
    {
        const int c4 = tid & 31;        // 4-float granule within row
        const int gg = c4 >> 1;         // 8-float group 0..15
        const int hl = c4 & 1;
        #pragma unroll
        for (int k = 0; k < 8; ++k) {
            const int r = k * 8 + (tid >> 5);             // row 0..63
            i32x2 w;
            w[0] = pack_f16(Lv[k][0], Lv[k][1]);
            w[1] = pack_f16(Lv[k][2], Lv[k][3]);
            *(i32x2*)&Asm[r * H_ + ((gg ^ (r & 15)) * 8) + hl * 4] = w;
        }
    }
    __syncthreads();

    // ---- phase 2: per-wave MFMA from LDS, 4 pairs (nu ascending => sp0 min) ----
    if (sp0 < SPH_) {
        #pragma unroll
        for (int p = 0; p < 4; ++p) {
            const int pp = (p == 0) ? pid0 : (p == 1) ? pid1 : (p == 2) ? pid2 : pid3;
            const int sp = (p == 0) ? sp0 : (p == 1) ? sp1 : (p == 2) ? sp2 : sp3;
            if (sp >= SPH_) continue;   // pair dead (wave-uniform)
            const int rank = pp * 16 + m;

            h16x8 bfr[2][4];
            #pragma unroll
            for (int part = 0; part < 2; ++part) {
                const unsigned short* rp = B2Tr + (size_t)(part * N_ + rank) * H_ + q * 8;
                #pragma unroll
                for (int sl = 0; sl < 4; ++sl)
                    bfr[part][sl] = *(const h16x8*)(rp + sl * 32);
            }
            float2 wl[4];
            #pragma unroll
            for (int r2 = 0; r2 < 4; ++r2) wl[r2] = lamjR[rank * 16 + q * 4 + r2];
            const float2 l16 = lam16R[rank];

            float2 zre = make_float2(0.f, 0.f), zim = make_float2(0.f, 0.f);
            for (int s = sp; s < SPH_; ++s) {
                const int row = s * 16 + m;               // 0..63
                h16x8 afr[4];
                #pragma unroll
                for (int sl = 0; sl < 4; ++sl) {
                    const int unit = (sl * 4 + q) ^ m;
                    afr[sl] = *(const h16x8*)&Asm[row * H_ + unit * 8];
                }
                // rescale accumulators by lam^16
                float2 t0 = zre;
                zre.x = l16.x * t0.x - l16.y * t0.y;
                zre.y = l16.x * t0.y + l16.y * t0.x;
                float2 t1 = zim;
                zim.x = l16.x * t1.x - l16.y * t1.y;
                zim.y = l16.x * t1.y + l16.y * t1.x;
                f32x4 acc = {0.f, 0.f, 0.f, 0.f};
                #pragma unroll
                for (int sl = 0; sl < 4; ++sl)
                    acc = __builtin_amdgcn_mfma_f32_16x16x32_f16(afr[sl], bfr[0][sl], acc, 0, 0, 0);
                #pragma unroll
                for (int r2 = 0; r2 < 4; ++r2) {
                    zre.x += wl[r2].x * acc[r2];
                    zre.y += wl[r2].y * acc[r2];
                }
                f32x4 acc2 = {0.f, 0.f, 0.f, 0.f};
                #pragma unroll
                for (int sl = 0; sl < 4; ++sl)
                    acc2 = __builtin_amdgcn_mfma_f32_16x16x32_f16(afr[sl], bfr[1][sl], acc2, 0, 0, 0);
                #pragma unroll
                for (int r2 = 0; r2 < 4; ++r2) {
                    zim.x += wl[r2].x * acc2[r2];
                    zim.y += wl[r2].y * acc2[r2];
                }
            }

            // reduce over q, rotate to sequence end, atomic complex partials
            float a = zre.x, b2 = zre.y, c2 = zim.x, d2 = zim.y;
            a  += __shfl_xor(a, 16);  a  += __shfl_xor(a, 32);
            b2 += __shfl_xor(b2, 16); b2 += __shfl_xor(b2, 32);
            c2 += __shfl_xor(c2, 16); c2 += __shfl_xor(c2, 32);
            d2 += __shfl_xor(d2, 16); d2 += __shfl_xor(d2, 32);
            if (lane < 16) {
                const int n = perm[rank];
                float2 lc = lamCCr[c * N_ + rank];
                if (h == 0) {                 // extra lam^64 for the lower half
                    float2 l32 = cmul(l16, l16);
                    lc = cmul(lc, cmul(l32, l32));
                }
                float prr = lc.x * a - lc.y * b2;
                float pri = lc.x * b2 + lc.y * a;
                float pir = lc.x * c2 - lc.y * d2;
                float pii = lc.x * d2 + lc.y * c2;
                atomicAdd(&X[(size_t)(b * N_ + n) * 2 + 0], prr - pii);
                atomicAdd(&X[(size_t)(b * N_ + n) * 2 + 1], pri + pir);
            }
        }
    }
}

// ---------------------------------------------------------------------------
// out: y[b,o] = sum_n (Cre*Xre - Cim*Xim) + sum_h D[o,h]*u[b,L-1,h]
// 512 threads, 4 threads per o, f32x4 loads, __shfl_xor(1,2) reduce.
// ---------------------------------------------------------------------------
__global__ __launch_bounds__(512)
void out_kernel(const float* __restrict__ X, const float* __restrict__ C_re,
                const float* __restrict__ C_im, const float* __restrict__ Dm,
                const float* __restrict__ u, float* __restrict__ out) {
    __shared__ __align__(16) float xre[N_];
    __shared__ __align__(16) float xim[N_];
    __shared__ __align__(16) float ul[H_];
    const int b = blockIdx.x;
    const int t = threadIdx.x;
    if (t < N_) {
        float2 x2 = *(const float2*)&X[(size_t)(b * N_ + t) * 2];
        xre[t] = x2.x;
        xim[t] = x2.y;
    }
    if (t < H_) ul[t] = u[((size_t)b * L_ + (L_ - 1)) * H_ + t];
    __syncthreads();
    const int o = t >> 2;              // 128 outputs
    const int part = t & 3;            // quarter of the reduction
    const float* cre = C_re + o * N_ + part * 64;
    const float* cim = C_im + o * N_ + part * 64;
    const float* xr  = xre + part * 64;
    const float* xi  = xim + part * 64;
    float s = 0.f;
    #pragma unroll
    for (int i = 0; i < 16; ++i) {
        f32x4 cr = *(const f32x4*)(cre + i * 4);
        f32x4 ci = *(const f32x4*)(cim + i * 4);
        f32x4 vr = *(const f32x4*)(xr + i * 4);
        f32x4 vi = *(const f32x4*)(xi + i * 4);
        s += cr[0] * vr[0] - ci[0] * vi[0];
        s += cr[1] * vr[1] - ci[1] * vi[1];
        s += cr[2] * vr[2] - ci[2] * vi[2];
        s += cr[3] * vr[3] - ci[3] * vi[3];
    }
    const float* dp = Dm + o * H_ + part * 32;
    const float* up = ul + part * 32;
    #pragma unroll
    for (int i = 0; i < 8; ++i) {
        f32x4 d4 = *(const f32x4*)(dp + i * 4);
        f32x4 u4 = *(const f32x4*)(up + i * 4);
        s += d4[0] * u4[0] + d4[1] * u4[1] + d4[2] * u4[2] + d4[3] * u4[3];
    }
    s += __shfl_xor(s, 1);
    s += __shfl_xor(s, 2);
    if (part == 0) out[b * O_ + o] = s;
}

extern "C" void kernel_launch(void* const* d_in, const int* in_sizes, int n_in,
                              void* d_out, int out_size, void* d_ws, size_t ws_size,
                              hipStream_t stream) {
    const float* u         = (const float*)d_in[2];   // dynamics_disturbance_time_window
    const float* nu_log    = (const float*)d_in[3];
    const float* theta_log = (const float*)d_in[4];
    const float* gamma_log = (const float*)d_in[5];
    const float* B_re      = (const float*)d_in[6];
    const float* B_im      = (const float*)d_in[7];
    const float* C_re      = (const float*)d_in[8];
    const float* C_im      = (const float*)d_in[9];
    const float* Dm        = (const float*)d_in[10];

    char* ws = (char*)d_ws;
    float*          X      = (float*)ws;                       // 131072 B
    unsigned short* B2Tr   = (unsigned short*)(ws + 131072);   // 131072 B
    float2*         lamjR  = (float2*)(ws + 262144);           // 32768 B
    float2*         lam16R = (float2*)(ws + 294912);           // 2048 B
    float2*         lamCCr = (float2*)(ws + 296960);           // 32768 B
    float*          nuR    = (float*)(ws + 329728);            // 1024 B
    int*            perm   = (int*)(ws + 330752);              // 1024 B

    prep_kernel<<<97, 256, 0, stream>>>(nu_log, theta_log, gamma_log, B_re, B_im,
                                        B2Tr, lamjR, lam16R, lamCCr, nuR, perm, X);
    scan_kernel<<<2048, 256, 0, stream>>>(u, B2Tr, lamjR, lam16R, lamCCr, nuR, perm, X);
    out_kernel<<<B_, 512, 0, stream>>>(X, C_re, C_im, Dm, u, (float*)d_out);
}

// Round 9
// 172.898 us; speedup vs baseline: 1.1706x; 1.1706x over previous
//
#include <hip/hip_runtime.h>
#include <hip/hip_bf16.h>
#include <math.h>
#include <stdint.h>

#define B_ 64
#define L_ 2048
#define H_ 128
#define O_ 128
#define N_ 256
#define CH_ 128      // timesteps per chunk
#define NCH_ 16      // chunks
#define SPC_ 8       // strips (16 t) per chunk

using f32x4 = __attribute__((ext_vector_type(4))) float;
using i32x4 = __attribute__((ext_vector_type(4))) int;
using i32x2 = __attribute__((ext_vector_type(2))) int;
using h16x8 = __attribute__((ext_vector_type(8))) _Float16;

__device__ __forceinline__ unsigned short f16_bits(float v) {
    _Float16 h = (_Float16)v;                 // RNE convert
    return __builtin_bit_cast(unsigned short, h);
}
__device__ __forceinline__ int pack_f16(float a, float b) {
    return (int)((unsigned)f16_bits(a) | ((unsigned)f16_bits(b) << 16));
}

// ---------------------------------------------------------------------------
// prep: every block self-computes the nu-sorted permutation (rank 0 = slowest
// decay), then fills its slice of: B2Tr (fp16 (gamma*B)^T, rank-ordered cols),
// lamjR[rank][j]=lam^(15-j), lam16R=lam^16, lamCCr[c][rank]=lam^(128*(15-c)),
// nuR, perm, and zeroes X.
// ---------------------------------------------------------------------------
__global__ void prep_kernel(const float* __restrict__ nu_log, const float* __restrict__ theta_log,
                            const float* __restrict__ gamma_log, const float* __restrict__ B_re,
                            const float* __restrict__ B_im, unsigned short* __restrict__ B2Tr,
                            float2* __restrict__ lamjR, float2* __restrict__ lam16R,
                            float2* __restrict__ lamCCr, float* __restrict__ nuR,
                            int* __restrict__ perm, float* __restrict__ X) {
    __shared__ float nu_s[N_];
    __shared__ int perm_s[N_];
    const int t = threadIdx.x;
    float nu = expf(nu_log[t]);
    nu_s[t] = nu;
    __syncthreads();
    {
        int rank = 0;
        for (int j = 0; j < N_; ++j) {
            float vj = nu_s[j];
            rank += (vj < nu || (vj == nu && j < t)) ? 1 : 0;
        }
        perm_s[rank] = t;
    }
    __syncthreads();
    const int bb = blockIdx.x;
    if (bb < 64) {
        #pragma unroll
        for (int kk = 0; kk < 4; ++kk) {
            int e = bb * 1024 + kk * 256 + t;       // 0..65535
            int part = e >> 15, rank = (e >> 7) & 255, h = e & 127;
            int n = perm_s[rank];
            float g = expf(gamma_log[n]);
            float v = (part ? B_im : B_re)[n * H_ + h] * g;
            B2Tr[e] = f16_bits(v);
        }
    } else if (bb == 64) {
        int r = t, n = perm_s[r];
        float nun = nu_s[n];
        double th = (double)expf(theta_log[n]);
        double rr = exp(-(double)nun);
        double sn, cs;
        sincos(th, &sn, &cs);
        double lre = rr * cs, lim = rr * sn;
        double pre = 1.0, pim = 0.0;
        for (int k = 0; k < 16; ++k) {
            lamjR[r * 16 + 15 - k] = make_float2((float)pre, (float)pim);
            double t1 = pre * lre - pim * lim, t2 = pre * lim + pim * lre;
            pre = t1; pim = t2;
        }
        lam16R[r] = make_float2((float)pre, (float)pim);   // lam^16
        nuR[r] = nun;
        perm[r] = n;
        double wre = pre, wim = pim;                        // -> lam^128
        for (int i = 0; i < 3; ++i) {
            double a = wre * wre - wim * wim, b2 = 2.0 * wre * wim;
            wre = a; wim = b2;
        }
        double are = 1.0, aim = 0.0;
        for (int c = 15; c >= 0; --c) {
            lamCCr[c * N_ + r] = make_float2((float)are, (float)aim);
            double a = are * wre - aim * wim, b2 = are * wim + aim * wre;
            are = a; aim = b2;
        }
    } else {
        int idx = (bb - 65) * 1024 + t * 4;                 // 32 blocks x 1024 floats
        f32x4 z = {0.f, 0.f, 0.f, 0.f};
        *(f32x4*)&X[idx] = z;
    }
}

// ---------------------------------------------------------------------------
// scan: block = (chunk c, b), 512 threads = 8 waves.  Round-4 structure (best
// measured, 172.5 total) with ONE change (round 9): u loads are system-scope
// (sc1) via inline asm.  Why: r8's counters showed scan WRITES 40.3 MB of HBM
// (vs ~1 MB of atomic payload) while fetching 43.5 MB — i.e. every u-read
// miss ALLOCATES in the Infinity Cache and evicts a DIRTY poison line (the
// harness's 3x268MB fills leave all 256MB of L3 dirty), dragging a ~1:1
// writeback stream behind the read and forcing mixed read/write HBM service
// (~2 TB/s effective — the stubborn ~31us).  nt (r7) is evict-FIRST but still
// allocates -> still writebacks, plus lost the ~23MB of L3 hits -> +8us.
// sc1 = system scope = NOT cached in L3: no allocation, no eviction, no
// writeback.  u has zero reuse so cacheability is worthless for it.
//  (a) bx = c*64 + b: spreads each chunk's 64 blocks across the 8 XCDs.
//  (b) wave g owns pairs {g, 15-g} (nu-rank balanced at hot chunks).
//  (c) gates computed BEFORE the asm loads so compiler vmcnt bookkeeping for
//      its own (nuR) loads stays exact.
// Phase 1: 8x global_load_dwordx4 sc1 (SGPR base + voffset tid*16 + k*8192),
// completion tied to the pack by an s_waitcnt vmcnt(0) asm with +v operands
// + sched_barrier(0) (rule-18 guard).  Pack to fp16, XOR-swizzled LDS image
// (unit = (c4>>1) ^ (r&15)), one barrier.
// Phase 2: per pair: z <- lam^16 z + sum_j lam^(15-j) Bu_j per strip, strips
// below the decay window (nu*(base_e-16s) > 35) skipped. Epilogue rotates by
// lamCC and atomicAdds complex x[b,n].
// ---------------------------------------------------------------------------
__global__ __launch_bounds__(512, 4)
void scan_kernel(const float* __restrict__ u, const unsigned short* __restrict__ B2Tr,
                 const float2* __restrict__ lamjR, const float2* __restrict__ lam16R,
                 const float2* __restrict__ lamCCr, const float* __restrict__ nuR,
                 const int* __restrict__ perm, float* __restrict__ X) {
    const int bx = blockIdx.x;
    const int c = bx >> 6;            // chunk 0..15 — each c spread over XCDs
    const int b = bx & 63;
    const int tid = threadIdx.x;

    __shared__ __align__(16) unsigned short Asm[CH_ * H_];   // 32 KB fp16 chunk image

    // ---- phase-2 gates FIRST (small uniform loads, ~L2 latency) ----
    const int g = tid >> 6;                // wave 0..7
    const int lane = tid & 63;
    const int m = lane & 15, q = lane >> 4;
    const int p0 = g, p1 = 15 - g;         // balanced pair assignment
    // strip alive iff nu*(base_e - 16s) <= 35  (e^-35 ~ 6e-16 truncation)
    const float base_e = 2032.0f - 128.0f * (float)c;
    const float nu0 = nuR[p0 * 16];
    const float nu1 = nuR[p1 * 16];
    int spA = (int)ceilf((base_e - 35.0f / nu0) * 0.0625f);
    if (spA < 0) spA = 0;
    int spB = (int)ceilf((base_e - 35.0f / nu1) * 0.0625f);
    if (spB < 0) spB = 0;

    // ---- phase 1: issue 8 sc1 (system-scope, L3-no-allocate) 16B loads ----
    const float* sbase = u + ((size_t)b * L_ + (size_t)(c * CH_)) * H_;  // block-uniform
    const unsigned vo = (unsigned)(tid * 16);                            // byte voffset
    f32x4 Lv0, Lv1, Lv2, Lv3, Lv4, Lv5, Lv6, Lv7;
    asm volatile(
        "global_load_dwordx4 %[d0], %[o0], %[sb] sc1\n\t"
        "global_load_dwordx4 %[d1], %[o1], %[sb] sc1\n\t"
        "global_load_dwordx4 %[d2], %[o2], %[sb] sc1\n\t"
        "global_load_dwordx4 %[d3], %[o3], %[sb] sc1\n\t"
        "global_load_dwordx4 %[d4], %[o4], %[sb] sc1\n\t"
        "global_load_dwordx4 %[d5], %[o5], %[sb] sc1\n\t"
        "global_load_dwordx4 %[d6], %[o6], %[sb] sc1\n\t"
        "global_load_dwordx4 %[d7], %[o7], %[sb] sc1"
        : [d0]"=&v"(Lv0), [d1]"=&v"(Lv1), [d2]"=&v"(Lv2), [d3]"=&v"(Lv3),
          [d4]"=&v"(Lv4), [d5]"=&v"(Lv5), [d6]"=&v"(Lv6), [d7]"=&v"(Lv7)
        : [o0]"v"(vo),            [o1]"v"(vo + 8192u),  [o2]"v"(vo + 16384u),
          [o3]"v"(vo + 24576u),   [o4]"v"(vo + 32768u), [o5]"v"(vo + 40960u),
          [o6]"v"(vo + 49152u),   [o7]"v"(vo + 57344u), [sb]"s"(sbase)
        : "memory");

    // ---- pack indices (VALU only, overlap load flight) ----
    const int c4 = tid & 31;            // 4-float granule within row
    const int gg = c4 >> 1;             // 8-float group 0..15
    const int half = c4 & 1;

    // ---- wait for the asm loads, tied by data dependency ----
    asm volatile("s_waitcnt vmcnt(0)"
                 : "+v"(Lv0), "+v"(Lv1), "+v"(Lv2), "+v"(Lv3),
                   "+v"(Lv4), "+v"(Lv5), "+v"(Lv6), "+v"(Lv7)
                 :: "memory");
    __builtin_amdgcn_sched_barrier(0);

    // ---- pack + swizzled LDS store ----
    #define PACKSTORE(K, LVK)                                                  \
    {                                                                          \
        const int r = K * 16 + (tid >> 5);                                     \
        i32x2 w;                                                               \
        w[0] = pack_f16(LVK[0], LVK[1]);                                       \
        w[1] = pack_f16(LVK[2], LVK[3]);                                       \
        *(i32x2*)&Asm[r * H_ + ((gg ^ (r & 15)) * 8) + half * 4] = w;          \
    }
    PACKSTORE(0, Lv0) PACKSTORE(1, Lv1) PACKSTORE(2, Lv2) PACKSTORE(3, Lv3)
    PACKSTORE(4, Lv4) PACKSTORE(5, Lv5) PACKSTORE(6, Lv6) PACKSTORE(7, Lv7)
    #undef PACKSTORE
    __syncthreads();

    // ---- phase 2: per-wave MFMA from LDS ----
    if (spA < SPC_) {                      // wave has live work (spA <= spB)
        #pragma unroll
        for (int p = 0; p < 2; ++p) {
            const int sp = p ? spB : spA;
            if (sp >= SPC_) continue;      // pair dead (wave-uniform)
            const int pp = p ? p1 : p0;
            const int rank = pp * 16 + m;

            h16x8 bfr[2][4];
            #pragma unroll
            for (int part = 0; part < 2; ++part) {
                const unsigned short* rp = B2Tr + (size_t)(part * N_ + rank) * H_ + q * 8;
                #pragma unroll
                for (int sl = 0; sl < 4; ++sl)
                    bfr[part][sl] = *(const h16x8*)(rp + sl * 32);
            }
            float2 wl[4];
            #pragma unroll
            for (int r2 = 0; r2 < 4; ++r2) wl[r2] = lamjR[rank * 16 + q * 4 + r2];
            const float2 l16 = lam16R[rank];

            float2 zre = make_float2(0.f, 0.f), zim = make_float2(0.f, 0.f);
            for (int s = sp; s < SPC_; ++s) {
                const int row = s * 16 + m;
                h16x8 afr[4];
                #pragma unroll
                for (int sl = 0; sl < 4; ++sl) {
                    const int unit = (sl * 4 + q) ^ m;
                    afr[sl] = *(const h16x8*)&Asm[row * H_ + unit * 8];
                }
                // rescale accumulators by lam^16
                float2 t0 = zre;
                zre.x = l16.x * t0.x - l16.y * t0.y;
                zre.y = l16.x * t0.y + l16.y * t0.x;
                float2 t1 = zim;
                zim.x = l16.x * t1.x - l16.y * t1.y;
                zim.y = l16.x * t1.y + l16.y * t1.x;
                f32x4 acc = {0.f, 0.f, 0.f, 0.f};
                #pragma unroll
                for (int sl = 0; sl < 4; ++sl)
                    acc = __builtin_amdgcn_mfma_f32_16x16x32_f16(afr[sl], bfr[0][sl], acc, 0, 0, 0);
                #pragma unroll
                for (int r2 = 0; r2 < 4; ++r2) {
                    zre.x += wl[r2].x * acc[r2];
                    zre.y += wl[r2].y * acc[r2];
                }
                f32x4 acc2 = {0.f, 0.f, 0.f, 0.f};
                #pragma unroll
                for (int sl = 0; sl < 4; ++sl)
                    acc2 = __builtin_amdgcn_mfma_f32_16x16x32_f16(afr[sl], bfr[1][sl], acc2, 0, 0, 0);
                #pragma unroll
                for (int r2 = 0; r2 < 4; ++r2) {
                    zim.x += wl[r2].x * acc2[r2];
                    zim.y += wl[r2].y * acc2[r2];
                }
            }

            // reduce over q, rotate by lamCC, atomic complex partials
            float a = zre.x, b2 = zre.y, c2 = zim.x, d2 = zim.y;
            a  += __shfl_xor(a, 16);  a  += __shfl_xor(a, 32);
            b2 += __shfl_xor(b2, 16); b2 += __shfl_xor(b2, 32);
            c2 += __shfl_xor(c2, 16); c2 += __shfl_xor(c2, 32);
            d2 += __shfl_xor(d2, 16); d2 += __shfl_xor(d2, 32);
            if (lane < 16) {
                const int n = perm[rank];
                float2 lc = lamCCr[c * N_ + rank];
                float prr = lc.x * a - lc.y * b2;
                float pri = lc.x * b2 + lc.y * a;
                float pir = lc.x * c2 - lc.y * d2;
                float pii = lc.x * d2 + lc.y * c2;
                atomicAdd(&X[(size_t)(b * N_ + n) * 2 + 0], prr - pii);
                atomicAdd(&X[(size_t)(b * N_ + n) * 2 + 1], pri + pir);
            }
        }
    }
}

// ---------------------------------------------------------------------------
// out: y[b,o] = sum_n (Cre*Xre - Cim*Xim) + sum_h D[o,h]*u[b,L-1,h]
// 512 threads, 4 threads per o, f32x4 loads, __shfl_xor(1,2) reduce.
// ---------------------------------------------------------------------------
__global__ __launch_bounds__(512)
void out_kernel(const float* __restrict__ X, const float* __restrict__ C_re,
                const float* __restrict__ C_im, const float* __restrict__ Dm,
                const float* __restrict__ u, float* __restrict__ out) {
    __shared__ __align__(16) float xre[N_];
    __shared__ __align__(16) float xim[N_];
    __shared__ __align__(16) float ul[H_];
    const int b = blockIdx.x;
    const int t = threadIdx.x;
    if (t < N_) {
        float2 x2 = *(const float2*)&X[(size_t)(b * N_ + t) * 2];
        xre[t] = x2.x;
        xim[t] = x2.y;
    }
    if (t < H_) ul[t] = u[((size_t)b * L_ + (L_ - 1)) * H_ + t];
    __syncthreads();
    const int o = t >> 2;              // 128 outputs
    const int part = t & 3;            // quarter of the reduction
    const float* cre = C_re + o * N_ + part * 64;
    const float* cim = C_im + o * N_ + part * 64;
    const float* xr  = xre + part * 64;
    const float* xi  = xim + part * 64;
    float s = 0.f;
    #pragma unroll
    for (int i = 0; i < 16; ++i) {
        f32x4 cr = *(const f32x4*)(cre + i * 4);
        f32x4 ci = *(const f32x4*)(cim + i * 4);
        f32x4 vr = *(const f32x4*)(xr + i * 4);
        f32x4 vi = *(const f32x4*)(xi + i * 4);
        s += cr[0] * vr[0] - ci[0] * vi[0];
        s += cr[1] * vr[1] - ci[1] * vi[1];
        s += cr[2] * vr[2] - ci[2] * vi[2];
        s += cr[3] * vr[3] - ci[3] * vi[3];
    }
    const float* dp = Dm + o * H_ + part * 32;
    const float* up = ul + part * 32;
    #pragma unroll
    for (int i = 0; i < 8; ++i) {
        f32x4 d4 = *(const f32x4*)(dp + i * 4);
        f32x4 u4 = *(const f32x4*)(up + i * 4);
        s += d4[0] * u4[0] + d4[1] * u4[1] + d4[2] * u4[2] + d4[3] * u4[3];
    }
    s += __shfl_xor(s, 1);
    s += __shfl_xor(s, 2);
    if (part == 0) out[b * O_ + o] = s;
}

extern "C" void kernel_launch(void* const* d_in, const int* in_sizes, int n_in,
                              void* d_out, int out_size, void* d_ws, size_t ws_size,
                              hipStream_t stream) {
    const float* u         = (const float*)d_in[2];   // dynamics_disturbance_time_window
    const float* nu_log    = (const float*)d_in[3];
    const float* theta_log = (const float*)d_in[4];
    const float* gamma_log = (const float*)d_in[5];
    const float* B_re      = (const float*)d_in[6];
    const float* B_im      = (const float*)d_in[7];
    const float* C_re      = (const float*)d_in[8];
    const float* C_im      = (const float*)d_in[9];
    const float* Dm        = (const float*)d_in[10];

    char* ws = (char*)d_ws;
    float*          X      = (float*)ws;                       // 131072 B
    unsigned short* B2Tr   = (unsigned short*)(ws + 131072);   // 131072 B
    float2*         lamjR  = (float2*)(ws + 262144);           // 32768 B
    float2*         lam16R = (float2*)(ws + 294912);           // 2048 B
    float2*         lamCCr = (float2*)(ws + 296960);           // 32768 B
    float*          nuR    = (float*)(ws + 329728);            // 1024 B
    int*            perm   = (int*)(ws + 330752);              // 1024 B

    prep_kernel<<<97, 256, 0, stream>>>(nu_log, theta_log, gamma_log, B_re, B_im,
                                        B2Tr, lamjR, lam16R, lamCCr, nuR, perm, X);
    scan_kernel<<<B_ * NCH_, 512, 0, stream>>>(u, B2Tr, lamjR, lam16R, lamCCr, nuR, perm, X);
    out_kernel<<<B_, 512, 0, stream>>>(X, C_re, C_im, Dm, u, (float*)d_out);
}